// Round 1
// baseline (991.638 us; speedup 1.0000x reference)
//
#include <hip/hip_runtime.h>
#include <math.h>

// ---------------- CSR build ----------------

__global__ void k_deg(const int* __restrict__ tgt, int* __restrict__ deg, int e) {
    int i = blockIdx.x * blockDim.x + threadIdx.x;
    if (i < e) atomicAdd(&deg[tgt[i]], 1);
}

// single-block exclusive scan (Hillis-Steele per 256-tile with running carry)
__global__ void k_scan(const int* __restrict__ deg, int* __restrict__ rowp,
                       int* __restrict__ pos, int n) {
    __shared__ int sm[256];
    __shared__ int carry_s;
    if (threadIdx.x == 0) carry_s = 0;
    __syncthreads();
    for (int base = 0; base < n; base += 256) {
        int i = base + threadIdx.x;
        int v = (i < n) ? deg[i] : 0;
        sm[threadIdx.x] = v;
        __syncthreads();
        for (int off = 1; off < 256; off <<= 1) {
            int t = (threadIdx.x >= off) ? sm[threadIdx.x - off] : 0;
            __syncthreads();
            sm[threadIdx.x] += t;
            __syncthreads();
        }
        int incl = sm[threadIdx.x];
        int excl = incl - v + carry_s;
        if (i < n) { rowp[i] = excl; pos[i] = excl; }
        __syncthreads();
        if (threadIdx.x == 255) carry_s += incl;   // incl of last thread == tile total
        __syncthreads();
    }
    if (threadIdx.x == 0) rowp[n] = carry_s;
}

__global__ void k_scatter(const int* __restrict__ src, const int* __restrict__ tgt,
                          const float* __restrict__ ea, int* __restrict__ pos,
                          int* __restrict__ col_src, float2* __restrict__ col_ea, int e) {
    int i = blockIdx.x * blockDim.x + threadIdx.x;
    if (i < e) {
        int t = tgt[i];
        int slot = atomicAdd(&pos[t], 1);
        col_src[slot] = src[i];
        col_ea[slot] = make_float2(ea[2 * i], ea[2 * i + 1]);
    }
}

// ---------------- Layer 1: fused transform + online-softmax aggregation ----------------
// wave per node; lane l owns features f0=2l, f1=2l+1 ; head h = l>>2 (8 c's over 4 lanes)

__global__ __launch_bounds__(256) void k_agg1(
    const float* __restrict__ x,          // [N,2]
    const int* __restrict__ rowp,         // [N+1]
    const int* __restrict__ col_src,      // [E]
    const float2* __restrict__ col_ea,    // [E]
    const float* __restrict__ W_l1, const float* __restrict__ b_l1,
    const float* __restrict__ W_r1, const float* __restrict__ b_r1,
    const float* __restrict__ W_e1,       // [2,128]
    const float* __restrict__ att1,       // [128]
    const float* __restrict__ bias1,      // [128]
    float* __restrict__ hpost,            // [N,128]  elu(out+bias)
    int n)
{
    int wid = (blockIdx.x * blockDim.x + threadIdx.x) >> 6;
    int lane = threadIdx.x & 63;
    if (wid >= n) return;
    int v = wid;
    int f0 = 2 * lane, f1 = 2 * lane + 1;

    float Wl00 = W_l1[f0], Wl10 = W_l1[128 + f0], bl0 = b_l1[f0];
    float Wl01 = W_l1[f1], Wl11 = W_l1[128 + f1], bl1 = b_l1[f1];
    float We00 = W_e1[f0], We10 = W_e1[128 + f0];
    float We01 = W_e1[f1], We11 = W_e1[128 + f1];
    float a0 = att1[f0], a1 = att1[f1];

    float xv0 = x[2 * v], xv1 = x[2 * v + 1];
    float xrA = xv0 * W_r1[f0] + xv1 * W_r1[128 + f0] + b_r1[f0];
    float xrB = xv0 * W_r1[f1] + xv1 * W_r1[128 + f1] + b_r1[f1];

    float mh = -INFINITY, lh = 0.f, acc0 = 0.f, acc1 = 0.f;
    int rs = rowp[v], re = rowp[v + 1];
    for (int cs = rs; cs < re; cs += 64) {
        int cnt = min(64, re - cs);
        int myu = 0; float2 mea = make_float2(0.f, 0.f); float2 mxs = make_float2(0.f, 0.f);
        if (lane < cnt) {
            myu = col_src[cs + lane];
            mea = col_ea[cs + lane];
            mxs = *(const float2*)&x[2 * myu];
        }
        for (int j = 0; j < cnt; ++j) {
            float xs0 = __shfl(mxs.x, j), xs1 = __shfl(mxs.y, j);
            float ea0 = __shfl(mea.x, j), ea1 = __shfl(mea.y, j);
            float xl0 = xs0 * Wl00 + xs1 * Wl10 + bl0;      // lin_l(x[src]) on the fly
            float xl1 = xs0 * Wl01 + xs1 * Wl11 + bl1;
            float m0 = xl0 + xrA + ea0 * We00 + ea1 * We10;
            float m1 = xl1 + xrB + ea0 * We01 + ea1 * We11;
            float ph = fmaxf(m0, 0.2f * m0) * a0 + fmaxf(m1, 0.2f * m1) * a1;
            ph += __shfl_xor(ph, 1);
            ph += __shfl_xor(ph, 2);                         // e_h replicated over 4-lane group
            float nm = fmaxf(mh, ph);
            float sc = __expf(mh - nm);                      // exp(-inf)=0 on first edge
            float p  = __expf(ph - nm);
            lh   = lh * sc + p;
            acc0 = acc0 * sc + p * xl0;
            acc1 = acc1 * sc + p * xl1;
            mh = nm;
        }
    }
    float r0, r1;
    if (re > rs) { float inv = 1.f / lh; r0 = acc0 * inv; r1 = acc1 * inv; }
    else { r0 = 0.f; r1 = 0.f; }
    r0 += bias1[f0]; r1 += bias1[f1];
    r0 = (r0 > 0.f) ? r0 : (__expf(r0) - 1.f);              // elu
    r1 = (r1 > 0.f) ? r1 : (__expf(r1) - 1.f);
    hpost[v * 128 + f0] = r0;
    hpost[v * 128 + f1] = r1;
}

// ---------------- Layer 2 node transforms: h @ W_l2 / W_r2 (+b), W in LDS ----------------

__global__ __launch_bounds__(256) void k_transform2(
    const float* __restrict__ hpost,  // [N,128]
    const float* __restrict__ W_l2, const float* __restrict__ b_l2,
    const float* __restrict__ W_r2, const float* __restrict__ b_r2,
    float* __restrict__ xl2, float* __restrict__ xr2, int n)
{
    __shared__ float Wl[128 * 64];
    __shared__ float Wr[128 * 64];
    for (int i = threadIdx.x; i < 128 * 64; i += 256) { Wl[i] = W_l2[i]; Wr[i] = W_r2[i]; }
    __syncthreads();
    int lane = threadIdx.x & 63;
    int wib = threadIdx.x >> 6;
    float bl = b_l2[lane], br = b_r2[lane];
    for (int v = blockIdx.x * 4 + wib; v < n; v += gridDim.x * 4) {
        float h0 = hpost[v * 128 + lane];
        float h1 = hpost[v * 128 + 64 + lane];
        float al = bl, ar = br;
#pragma unroll 16
        for (int k = 0; k < 64; ++k) {
            float hk = __shfl(h0, k);
            al += hk * Wl[k * 64 + lane];
            ar += hk * Wr[k * 64 + lane];
        }
#pragma unroll 16
        for (int k = 0; k < 64; ++k) {
            float hk = __shfl(h1, k);
            al += hk * Wl[(64 + k) * 64 + lane];
            ar += hk * Wr[(64 + k) * 64 + lane];
        }
        xl2[v * 64 + lane] = al;
        xr2[v * 64 + lane] = ar;
    }
}

// ---------------- Layer 2 aggregation: wave per node, lane = feature ----------------

__global__ __launch_bounds__(256) void k_agg2(
    const float* __restrict__ xl2,   // [N,64]
    const float* __restrict__ xr2,   // [N,64]
    const int* __restrict__ rowp,
    const int* __restrict__ col_src,
    const float2* __restrict__ col_ea,
    const float* __restrict__ W_e2,  // [2,64]
    const float* __restrict__ att2,  // [64]
    const float* __restrict__ bias2, // [64]
    float* __restrict__ h2,          // [N,64]
    int n)
{
    int wid = (blockIdx.x * blockDim.x + threadIdx.x) >> 6;
    int lane = threadIdx.x & 63;
    if (wid >= n) return;
    int v = wid;
    float We0 = W_e2[lane], We1 = W_e2[64 + lane];
    float a = att2[lane];
    float xr = xr2[v * 64 + lane];
    float mh = -INFINITY, lh = 0.f, acc = 0.f;
    int rs = rowp[v], re = rowp[v + 1];
    for (int cs = rs; cs < re; cs += 64) {
        int cnt = min(64, re - cs);
        int myu = 0; float2 mea = make_float2(0.f, 0.f);
        if (lane < cnt) { myu = col_src[cs + lane]; mea = col_ea[cs + lane]; }
        for (int j = 0; j < cnt; ++j) {
            int u = __shfl(myu, j);
            float ea0 = __shfl(mea.x, j), ea1 = __shfl(mea.y, j);
            float xl = xl2[u * 64 + lane];
            float m = xl + xr + ea0 * We0 + ea1 * We1;
            float ph = fmaxf(m, 0.2f * m) * a;
            ph += __shfl_xor(ph, 1);
            ph += __shfl_xor(ph, 2);
            ph += __shfl_xor(ph, 4);
            ph += __shfl_xor(ph, 8);                 // e_h over 16-lane group
            float nm = fmaxf(mh, ph);
            float sc = __expf(mh - nm);
            float p = __expf(ph - nm);
            lh = lh * sc + p;
            acc = acc * sc + p * xl;
            mh = nm;
        }
    }
    float r = (re > rs) ? acc / lh : 0.f;
    h2[v * 64 + lane] = r + bias2[lane];
}

// ---------------- Mean pool over graphs ----------------

__global__ void k_pool(const float* __restrict__ h2, const int* __restrict__ batch,
                       float* __restrict__ sums, float* __restrict__ cnt, int n) {
    int wid = (blockIdx.x * blockDim.x + threadIdx.x) >> 6;
    int lane = threadIdx.x & 63;
    if (wid >= n) return;
    int g = batch[wid];
    atomicAdd(&sums[g * 64 + lane], h2[wid * 64 + lane]);
    if (lane == 0) atomicAdd(&cnt[g], 1.f);
}

__global__ void k_final(const float* __restrict__ sums, const float* __restrict__ cnt,
                        float* __restrict__ out, int g) {
    int i = blockIdx.x * blockDim.x + threadIdx.x;
    if (i < g * 64) out[i] = sums[i] / fmaxf(cnt[i >> 6], 1.f);
}

// ---------------- launch ----------------

extern "C" void kernel_launch(void* const* d_in, const int* in_sizes, int n_in,
                              void* d_out, int out_size, void* d_ws, size_t ws_size,
                              hipStream_t stream) {
    const float* x     = (const float*)d_in[0];
    const float* ea    = (const float*)d_in[1];
    const float* W_l1  = (const float*)d_in[2];
    const float* b_l1  = (const float*)d_in[3];
    const float* W_r1  = (const float*)d_in[4];
    const float* b_r1  = (const float*)d_in[5];
    const float* W_e1  = (const float*)d_in[6];
    const float* att1  = (const float*)d_in[7];
    const float* bias1 = (const float*)d_in[8];
    const float* W_l2  = (const float*)d_in[9];
    const float* b_l2  = (const float*)d_in[10];
    const float* W_r2  = (const float*)d_in[11];
    const float* b_r2  = (const float*)d_in[12];
    const float* W_e2  = (const float*)d_in[13];
    const float* att2  = (const float*)d_in[14];
    const float* bias2 = (const float*)d_in[15];
    const int* eidx    = (const int*)d_in[16];
    const int* batch   = (const int*)d_in[17];

    int n = in_sizes[0] / 2;     // 50000
    int e = in_sizes[16] / 2;    // 800000
    int g = out_size / 64;       // 64
    const int* srcI = eidx;
    const int* tgtI = eidx + e;

    char* w = (char*)d_ws;
    size_t off = 0;
    auto take = [&](size_t bytes) -> char* {
        size_t a = (off + 255) & ~(size_t)255;
        off = a + bytes;
        return w + a;
    };
    float*  hpost   = (float*)take((size_t)n * 128 * 4);
    float*  xl2     = (float*)take((size_t)n * 64 * 4);
    float*  xr2     = (float*)take((size_t)n * 64 * 4);
    float*  h2      = (float*)take((size_t)n * 64 * 4);
    int*    deg     = (int*)take((size_t)n * 4);
    int*    pos     = (int*)take((size_t)n * 4);
    int*    rowp    = (int*)take((size_t)(n + 1) * 4);
    int*    col_src = (int*)take((size_t)e * 4);
    float2* col_ea  = (float2*)take((size_t)e * 8);
    float*  sums    = (float*)take((size_t)g * 64 * 4);
    float*  cnt     = (float*)take((size_t)g * 4);

    hipMemsetAsync(deg, 0, (size_t)n * 4, stream);
    hipMemsetAsync(sums, 0, (size_t)g * 64 * 4, stream);
    hipMemsetAsync(cnt, 0, (size_t)g * 4, stream);

    k_deg<<<(e + 255) / 256, 256, 0, stream>>>(tgtI, deg, e);
    k_scan<<<1, 256, 0, stream>>>(deg, rowp, pos, n);
    k_scatter<<<(e + 255) / 256, 256, 0, stream>>>(srcI, tgtI, ea, pos, col_src, col_ea, e);

    int nwaveblocks = (n * 64 + 255) / 256;
    k_agg1<<<nwaveblocks, 256, 0, stream>>>(x, rowp, col_src, col_ea,
                                            W_l1, b_l1, W_r1, b_r1, W_e1, att1, bias1,
                                            hpost, n);
    k_transform2<<<1024, 256, 0, stream>>>(hpost, W_l2, b_l2, W_r2, b_r2, xl2, xr2, n);
    k_agg2<<<nwaveblocks, 256, 0, stream>>>(xl2, xr2, rowp, col_src, col_ea,
                                            W_e2, att2, bias2, h2, n);
    k_pool<<<nwaveblocks, 256, 0, stream>>>(h2, batch, sums, cnt, n);
    k_final<<<(g * 64 + 255) / 256, 256, 0, stream>>>(sums, cnt, (float*)d_out, g);
}

// Round 2
// 385.069 us; speedup vs baseline: 2.5752x; 2.5752x over previous
//
#include <hip/hip_runtime.h>
#include <math.h>

// ---------------- CSR build ----------------

__global__ void k_deg(const int* __restrict__ tgt, int* __restrict__ deg, int e) {
    int i = blockIdx.x * blockDim.x + threadIdx.x;
    if (i < e) atomicAdd(&deg[tgt[i]], 1);
}

// parallel scan, stage A: per-block (256-elem tile) exclusive scan via wave shuffles
__global__ __launch_bounds__(256) void k_scanA(const int* __restrict__ deg,
                                               int* __restrict__ excl,   // rowp used as tile-local excl
                                               int* __restrict__ bsum, int n) {
    int i = blockIdx.x * 256 + threadIdx.x;
    int lane = threadIdx.x & 63, wv = threadIdx.x >> 6;
    int v = (i < n) ? deg[i] : 0;
    int incl = v;
#pragma unroll
    for (int off = 1; off < 64; off <<= 1) {
        int t = __shfl_up(incl, off);
        if (lane >= off) incl += t;
    }
    __shared__ int ws[4];
    if (lane == 63) ws[wv] = incl;
    __syncthreads();
    int prefix = 0;
    for (int k = 0; k < wv; ++k) prefix += ws[k];
    if (i < n) excl[i] = prefix + incl - v;
    if (threadIdx.x == 255) bsum[blockIdx.x] = prefix + incl;
}

// stage B: single-block scan of block sums (nb up to many tiles, loop w/ carry)
__global__ __launch_bounds__(256) void k_scanB(const int* __restrict__ bsum, int* __restrict__ boff,
                                               int* __restrict__ rowp, int nb, int n) {
    __shared__ int ws[4];
    __shared__ int carry_s;
    int lane = threadIdx.x & 63, wv = threadIdx.x >> 6;
    if (threadIdx.x == 0) carry_s = 0;
    __syncthreads();
    for (int base = 0; base < nb; base += 256) {
        int i = base + threadIdx.x;
        int v = (i < nb) ? bsum[i] : 0;
        int incl = v;
#pragma unroll
        for (int off = 1; off < 64; off <<= 1) {
            int t = __shfl_up(incl, off);
            if (lane >= off) incl += t;
        }
        if (lane == 63) ws[wv] = incl;
        __syncthreads();
        int prefix = carry_s;
        for (int k = 0; k < wv; ++k) prefix += ws[k];
        if (i < nb) boff[i] = prefix + incl - v;
        __syncthreads();
        if (threadIdx.x == 255) carry_s = prefix + incl;
        __syncthreads();
    }
    if (threadIdx.x == 0) rowp[n] = carry_s;
}

// stage C: add block offsets; produce rowp and pos
__global__ void k_scanC(int* __restrict__ rowp, int* __restrict__ pos,
                        const int* __restrict__ boff, int n) {
    int i = blockIdx.x * 256 + threadIdx.x;
    if (i < n) {
        int r = rowp[i] + boff[blockIdx.x];
        rowp[i] = r;
        pos[i] = r;
    }
}

__global__ void k_scatter(const int* __restrict__ src, const int* __restrict__ tgt,
                          const float* __restrict__ ea, int* __restrict__ pos,
                          int* __restrict__ col_src, float2* __restrict__ col_ea, int e) {
    int i = blockIdx.x * blockDim.x + threadIdx.x;
    if (i < e) {
        int t = tgt[i];
        int slot = atomicAdd(&pos[t], 1);
        col_src[slot] = src[i];
        col_ea[slot] = make_float2(ea[2 * i], ea[2 * i + 1]);
    }
}

// ---------------- Layer 1: fused transform + online-softmax aggregation ----------------
// wave per node; lane l owns features f0=2l, f1=2l+1 ; head h = l>>2 (8 c's over 4 lanes)

__global__ __launch_bounds__(256) void k_agg1(
    const float* __restrict__ x,          // [N,2]
    const int* __restrict__ rowp,         // [N+1]
    const int* __restrict__ col_src,      // [E]
    const float2* __restrict__ col_ea,    // [E]
    const float* __restrict__ W_l1, const float* __restrict__ b_l1,
    const float* __restrict__ W_r1, const float* __restrict__ b_r1,
    const float* __restrict__ W_e1,       // [2,128]
    const float* __restrict__ att1,       // [128]
    const float* __restrict__ bias1,      // [128]
    float* __restrict__ hpost,            // [N,128]  elu(out+bias)
    int n)
{
    int wid = (blockIdx.x * blockDim.x + threadIdx.x) >> 6;
    int lane = threadIdx.x & 63;
    if (wid >= n) return;
    int v = wid;
    int f0 = 2 * lane, f1 = 2 * lane + 1;

    float Wl00 = W_l1[f0], Wl10 = W_l1[128 + f0], bl0 = b_l1[f0];
    float Wl01 = W_l1[f1], Wl11 = W_l1[128 + f1], bl1 = b_l1[f1];
    float We00 = W_e1[f0], We10 = W_e1[128 + f0];
    float We01 = W_e1[f1], We11 = W_e1[128 + f1];
    float a0 = att1[f0], a1 = att1[f1];

    float xv0 = x[2 * v], xv1 = x[2 * v + 1];
    float xrA = xv0 * W_r1[f0] + xv1 * W_r1[128 + f0] + b_r1[f0];
    float xrB = xv0 * W_r1[f1] + xv1 * W_r1[128 + f1] + b_r1[f1];

    float mh = -INFINITY, lh = 0.f, acc0 = 0.f, acc1 = 0.f;
    int rs = rowp[v], re = rowp[v + 1];
    for (int cs = rs; cs < re; cs += 64) {
        int cnt = min(64, re - cs);
        int myu = 0; float2 mea = make_float2(0.f, 0.f); float2 mxs = make_float2(0.f, 0.f);
        if (lane < cnt) {
            myu = col_src[cs + lane];
            mea = col_ea[cs + lane];
            mxs = *(const float2*)&x[2 * myu];
        }
        for (int j = 0; j < cnt; ++j) {
            float xs0 = __shfl(mxs.x, j), xs1 = __shfl(mxs.y, j);
            float ea0 = __shfl(mea.x, j), ea1 = __shfl(mea.y, j);
            float xl0 = xs0 * Wl00 + xs1 * Wl10 + bl0;      // lin_l(x[src]) on the fly
            float xl1 = xs0 * Wl01 + xs1 * Wl11 + bl1;
            float m0 = xl0 + xrA + ea0 * We00 + ea1 * We10;
            float m1 = xl1 + xrB + ea0 * We01 + ea1 * We11;
            float ph = fmaxf(m0, 0.2f * m0) * a0 + fmaxf(m1, 0.2f * m1) * a1;
            ph += __shfl_xor(ph, 1);
            ph += __shfl_xor(ph, 2);                         // e_h replicated over 4-lane group
            float nm = fmaxf(mh, ph);
            float sc = __expf(mh - nm);                      // exp(-inf)=0 on first edge
            float p  = __expf(ph - nm);
            lh   = lh * sc + p;
            acc0 = acc0 * sc + p * xl0;
            acc1 = acc1 * sc + p * xl1;
            mh = nm;
        }
    }
    float r0, r1;
    if (re > rs) { float inv = 1.f / lh; r0 = acc0 * inv; r1 = acc1 * inv; }
    else { r0 = 0.f; r1 = 0.f; }
    r0 += bias1[f0]; r1 += bias1[f1];
    r0 = (r0 > 0.f) ? r0 : (__expf(r0) - 1.f);              // elu
    r1 = (r1 > 0.f) ? r1 : (__expf(r1) - 1.f);
    hpost[v * 128 + f0] = r0;
    hpost[v * 128 + f1] = r1;
}

// ---------------- Layer 2 node transforms: h @ W_l2 / W_r2 (+b), W in LDS ----------------

__global__ __launch_bounds__(256) void k_transform2(
    const float* __restrict__ hpost,  // [N,128]
    const float* __restrict__ W_l2, const float* __restrict__ b_l2,
    const float* __restrict__ W_r2, const float* __restrict__ b_r2,
    float* __restrict__ xl2, float* __restrict__ xr2, int n)
{
    __shared__ float Wl[128 * 64];
    __shared__ float Wr[128 * 64];
    for (int i = threadIdx.x; i < 128 * 64; i += 256) { Wl[i] = W_l2[i]; Wr[i] = W_r2[i]; }
    __syncthreads();
    int lane = threadIdx.x & 63;
    int wib = threadIdx.x >> 6;
    float bl = b_l2[lane], br = b_r2[lane];
    for (int v = blockIdx.x * 4 + wib; v < n; v += gridDim.x * 4) {
        float h0 = hpost[v * 128 + lane];
        float h1 = hpost[v * 128 + 64 + lane];
        float al = bl, ar = br;
#pragma unroll 16
        for (int k = 0; k < 64; ++k) {
            float hk = __shfl(h0, k);
            al += hk * Wl[k * 64 + lane];
            ar += hk * Wr[k * 64 + lane];
        }
#pragma unroll 16
        for (int k = 0; k < 64; ++k) {
            float hk = __shfl(h1, k);
            al += hk * Wl[(64 + k) * 64 + lane];
            ar += hk * Wr[(64 + k) * 64 + lane];
        }
        xl2[v * 64 + lane] = al;
        xr2[v * 64 + lane] = ar;
    }
}

// ---------------- Layer 2 aggregation: wave per node, lane = feature ----------------

__global__ __launch_bounds__(256) void k_agg2(
    const float* __restrict__ xl2,   // [N,64]
    const float* __restrict__ xr2,   // [N,64]
    const int* __restrict__ rowp,
    const int* __restrict__ col_src,
    const float2* __restrict__ col_ea,
    const float* __restrict__ W_e2,  // [2,64]
    const float* __restrict__ att2,  // [64]
    const float* __restrict__ bias2, // [64]
    float* __restrict__ h2,          // [N,64]
    int n)
{
    int wid = (blockIdx.x * blockDim.x + threadIdx.x) >> 6;
    int lane = threadIdx.x & 63;
    if (wid >= n) return;
    int v = wid;
    float We0 = W_e2[lane], We1 = W_e2[64 + lane];
    float a = att2[lane];
    float xr = xr2[v * 64 + lane];
    float mh = -INFINITY, lh = 0.f, acc = 0.f;
    int rs = rowp[v], re = rowp[v + 1];
    for (int cs = rs; cs < re; cs += 64) {
        int cnt = min(64, re - cs);
        int myu = 0; float2 mea = make_float2(0.f, 0.f);
        if (lane < cnt) { myu = col_src[cs + lane]; mea = col_ea[cs + lane]; }
        for (int j = 0; j < cnt; ++j) {
            int u = __shfl(myu, j);
            float ea0 = __shfl(mea.x, j), ea1 = __shfl(mea.y, j);
            float xl = xl2[u * 64 + lane];
            float m = xl + xr + ea0 * We0 + ea1 * We1;
            float ph = fmaxf(m, 0.2f * m) * a;
            ph += __shfl_xor(ph, 1);
            ph += __shfl_xor(ph, 2);
            ph += __shfl_xor(ph, 4);
            ph += __shfl_xor(ph, 8);                 // e_h over 16-lane group
            float nm = fmaxf(mh, ph);
            float sc = __expf(mh - nm);
            float p = __expf(ph - nm);
            lh = lh * sc + p;
            acc = acc * sc + p * xl;
            mh = nm;
        }
    }
    float r = (re > rs) ? acc / lh : 0.f;
    h2[v * 64 + lane] = r + bias2[lane];
}

// ---------------- Mean pool over graphs (batch is SORTED: segmented reduce) ----------------
// one wave per contiguous node chunk; flush one atomicAdd per graph-run

__global__ __launch_bounds__(256) void k_pool2(const float* __restrict__ h2,
                                               const int* __restrict__ batch,
                                               float* __restrict__ sums, float* __restrict__ cnt,
                                               int n, int chunk) {
    int w = (blockIdx.x * blockDim.x + threadIdx.x) >> 6;
    int lane = threadIdx.x & 63;
    int start = w * chunk;
    if (start >= n) return;
    int end = min(n, start + chunk);
    int g = batch[start];
    float acc = 0.f;
    int c = 0;
    for (int v = start; v < end; ++v) {
        int bg = batch[v];
        if (bg != g) {
            atomicAdd(&sums[g * 64 + lane], acc);
            if (lane == 0) atomicAdd(&cnt[g], (float)c);
            acc = 0.f; c = 0; g = bg;
        }
        acc += h2[(size_t)v * 64 + lane];
        ++c;
    }
    atomicAdd(&sums[g * 64 + lane], acc);
    if (lane == 0) atomicAdd(&cnt[g], (float)c);
}

__global__ void k_final(const float* __restrict__ sums, const float* __restrict__ cnt,
                        float* __restrict__ out, int g) {
    int i = blockIdx.x * blockDim.x + threadIdx.x;
    if (i < g * 64) out[i] = sums[i] / fmaxf(cnt[i >> 6], 1.f);
}

// ---------------- launch ----------------

extern "C" void kernel_launch(void* const* d_in, const int* in_sizes, int n_in,
                              void* d_out, int out_size, void* d_ws, size_t ws_size,
                              hipStream_t stream) {
    const float* x     = (const float*)d_in[0];
    const float* ea    = (const float*)d_in[1];
    const float* W_l1  = (const float*)d_in[2];
    const float* b_l1  = (const float*)d_in[3];
    const float* W_r1  = (const float*)d_in[4];
    const float* b_r1  = (const float*)d_in[5];
    const float* W_e1  = (const float*)d_in[6];
    const float* att1  = (const float*)d_in[7];
    const float* bias1 = (const float*)d_in[8];
    const float* W_l2  = (const float*)d_in[9];
    const float* b_l2  = (const float*)d_in[10];
    const float* W_r2  = (const float*)d_in[11];
    const float* b_r2  = (const float*)d_in[12];
    const float* W_e2  = (const float*)d_in[13];
    const float* att2  = (const float*)d_in[14];
    const float* bias2 = (const float*)d_in[15];
    const int* eidx    = (const int*)d_in[16];
    const int* batch   = (const int*)d_in[17];

    int n = in_sizes[0] / 2;     // 50000
    int e = in_sizes[16] / 2;    // 800000
    int g = out_size / 64;       // 64
    const int* srcI = eidx;
    const int* tgtI = eidx + e;
    int nb = (n + 255) / 256;    // scan tiles

    char* w = (char*)d_ws;
    size_t off = 0;
    auto take = [&](size_t bytes) -> char* {
        size_t a = (off + 255) & ~(size_t)255;
        off = a + bytes;
        return w + a;
    };
    float*  hpost   = (float*)take((size_t)n * 128 * 4);
    float*  xl2     = (float*)take((size_t)n * 64 * 4);
    float*  xr2     = (float*)take((size_t)n * 64 * 4);
    float*  h2      = (float*)take((size_t)n * 64 * 4);
    int*    deg     = (int*)take((size_t)n * 4);
    int*    pos     = (int*)take((size_t)n * 4);
    int*    rowp    = (int*)take((size_t)(n + 1) * 4);
    int*    col_src = (int*)take((size_t)e * 4);
    float2* col_ea  = (float2*)take((size_t)e * 8);
    float*  sums    = (float*)take((size_t)g * 64 * 4);
    float*  cnt     = (float*)take((size_t)g * 4);
    int*    bsum    = (int*)take((size_t)nb * 4);
    int*    boff    = (int*)take((size_t)nb * 4);

    hipMemsetAsync(deg, 0, (size_t)n * 4, stream);
    hipMemsetAsync(sums, 0, (size_t)g * 64 * 4, stream);
    hipMemsetAsync(cnt, 0, (size_t)g * 4, stream);

    k_deg<<<(e + 255) / 256, 256, 0, stream>>>(tgtI, deg, e);
    k_scanA<<<nb, 256, 0, stream>>>(deg, rowp, bsum, n);
    k_scanB<<<1, 256, 0, stream>>>(bsum, boff, rowp, nb, n);
    k_scanC<<<nb, 256, 0, stream>>>(rowp, pos, boff, n);
    k_scatter<<<(e + 255) / 256, 256, 0, stream>>>(srcI, tgtI, ea, pos, col_src, col_ea, e);

    int nwaveblocks = (n * 64 + 255) / 256;
    k_agg1<<<nwaveblocks, 256, 0, stream>>>(x, rowp, col_src, col_ea,
                                            W_l1, b_l1, W_r1, b_r1, W_e1, att1, bias1,
                                            hpost, n);
    k_transform2<<<1024, 256, 0, stream>>>(hpost, W_l2, b_l2, W_r2, b_r2, xl2, xr2, n);
    k_agg2<<<nwaveblocks, 256, 0, stream>>>(xl2, xr2, rowp, col_src, col_ea,
                                            W_e2, att2, bias2, h2, n);

    int pool_waves = 1024;
    int pool_chunk = (n + pool_waves - 1) / pool_waves;
    k_pool2<<<pool_waves / 4, 256, 0, stream>>>(h2, batch, sums, cnt, n, pool_chunk);
    k_final<<<(g * 64 + 255) / 256, 256, 0, stream>>>(sums, cnt, (float*)d_out, g);
}

// Round 3
// 312.406 us; speedup vs baseline: 3.1742x; 1.2326x over previous
//
#include <hip/hip_runtime.h>
#include <math.h>

// ---------------- CSR build ----------------

__global__ void k_deg(const int* __restrict__ tgt, int* __restrict__ deg, int e) {
    int i = blockIdx.x * blockDim.x + threadIdx.x;
    if (i < e) atomicAdd(&deg[tgt[i]], 1);
}

// parallel scan, stage A: per-block (256-elem tile) exclusive scan via wave shuffles
__global__ __launch_bounds__(256) void k_scanA(const int* __restrict__ deg,
                                               int* __restrict__ excl,
                                               int* __restrict__ bsum, int n) {
    int i = blockIdx.x * 256 + threadIdx.x;
    int lane = threadIdx.x & 63, wv = threadIdx.x >> 6;
    int v = (i < n) ? deg[i] : 0;
    int incl = v;
#pragma unroll
    for (int off = 1; off < 64; off <<= 1) {
        int t = __shfl_up(incl, off);
        if (lane >= off) incl += t;
    }
    __shared__ int ws[4];
    if (lane == 63) ws[wv] = incl;
    __syncthreads();
    int prefix = 0;
    for (int k = 0; k < wv; ++k) prefix += ws[k];
    if (i < n) excl[i] = prefix + incl - v;
    if (threadIdx.x == 255) bsum[blockIdx.x] = prefix + incl;
}

__global__ __launch_bounds__(256) void k_scanB(const int* __restrict__ bsum, int* __restrict__ boff,
                                               int* __restrict__ rowp, int nb, int n) {
    __shared__ int ws[4];
    __shared__ int carry_s;
    int lane = threadIdx.x & 63, wv = threadIdx.x >> 6;
    if (threadIdx.x == 0) carry_s = 0;
    __syncthreads();
    for (int base = 0; base < nb; base += 256) {
        int i = base + threadIdx.x;
        int v = (i < nb) ? bsum[i] : 0;
        int incl = v;
#pragma unroll
        for (int off = 1; off < 64; off <<= 1) {
            int t = __shfl_up(incl, off);
            if (lane >= off) incl += t;
        }
        if (lane == 63) ws[wv] = incl;
        __syncthreads();
        int prefix = carry_s;
        for (int k = 0; k < wv; ++k) prefix += ws[k];
        if (i < nb) boff[i] = prefix + incl - v;
        __syncthreads();
        if (threadIdx.x == 255) carry_s = prefix + incl;
        __syncthreads();
    }
    if (threadIdx.x == 0) rowp[n] = carry_s;
}

__global__ void k_scanC(int* __restrict__ rowp, int* __restrict__ pos,
                        const int* __restrict__ boff, int n) {
    int i = blockIdx.x * 256 + threadIdx.x;
    if (i < n) {
        int r = rowp[i] + boff[blockIdx.x];
        rowp[i] = r;
        pos[i] = r;
    }
}

__global__ void k_scatter(const int* __restrict__ src, const int* __restrict__ tgt,
                          const float* __restrict__ ea, int* __restrict__ pos,
                          int* __restrict__ col_src, float2* __restrict__ col_ea, int e) {
    int i = blockIdx.x * blockDim.x + threadIdx.x;
    if (i < e) {
        int t = tgt[i];
        int slot = atomicAdd(&pos[t], 1);
        col_src[slot] = src[i];
        col_ea[slot] = make_float2(ea[2 * i], ea[2 * i + 1]);
    }
}

// ---------------- Layer 1: fused transform + online-softmax aggregation ----------------

__global__ __launch_bounds__(256) void k_agg1(
    const float* __restrict__ x,
    const int* __restrict__ rowp,
    const int* __restrict__ col_src,
    const float2* __restrict__ col_ea,
    const float* __restrict__ W_l1, const float* __restrict__ b_l1,
    const float* __restrict__ W_r1, const float* __restrict__ b_r1,
    const float* __restrict__ W_e1,
    const float* __restrict__ att1,
    const float* __restrict__ bias1,
    float* __restrict__ hpost,
    int n)
{
    int wid = (blockIdx.x * blockDim.x + threadIdx.x) >> 6;
    int lane = threadIdx.x & 63;
    if (wid >= n) return;
    int v = wid;
    int f0 = 2 * lane, f1 = 2 * lane + 1;

    float Wl00 = W_l1[f0], Wl10 = W_l1[128 + f0], bl0 = b_l1[f0];
    float Wl01 = W_l1[f1], Wl11 = W_l1[128 + f1], bl1 = b_l1[f1];
    float We00 = W_e1[f0], We10 = W_e1[128 + f0];
    float We01 = W_e1[f1], We11 = W_e1[128 + f1];
    float a0 = att1[f0], a1 = att1[f1];

    float xv0 = x[2 * v], xv1 = x[2 * v + 1];
    float xrA = xv0 * W_r1[f0] + xv1 * W_r1[128 + f0] + b_r1[f0];
    float xrB = xv0 * W_r1[f1] + xv1 * W_r1[128 + f1] + b_r1[f1];

    float mh = -INFINITY, lh = 0.f, acc0 = 0.f, acc1 = 0.f;
    int rs = rowp[v], re = rowp[v + 1];
    for (int cs = rs; cs < re; cs += 64) {
        int cnt = min(64, re - cs);
        int myu = 0; float2 mea = make_float2(0.f, 0.f); float2 mxs = make_float2(0.f, 0.f);
        if (lane < cnt) {
            myu = col_src[cs + lane];
            mea = col_ea[cs + lane];
            mxs = *(const float2*)&x[2 * myu];
        }
        for (int j = 0; j < cnt; ++j) {
            float xs0 = __shfl(mxs.x, j), xs1 = __shfl(mxs.y, j);
            float ea0 = __shfl(mea.x, j), ea1 = __shfl(mea.y, j);
            float xl0 = xs0 * Wl00 + xs1 * Wl10 + bl0;
            float xl1 = xs0 * Wl01 + xs1 * Wl11 + bl1;
            float m0 = xl0 + xrA + ea0 * We00 + ea1 * We10;
            float m1 = xl1 + xrB + ea0 * We01 + ea1 * We11;
            float ph = fmaxf(m0, 0.2f * m0) * a0 + fmaxf(m1, 0.2f * m1) * a1;
            ph += __shfl_xor(ph, 1);
            ph += __shfl_xor(ph, 2);
            float nm = fmaxf(mh, ph);
            float sc = __expf(mh - nm);
            float p  = __expf(ph - nm);
            lh   = lh * sc + p;
            acc0 = acc0 * sc + p * xl0;
            acc1 = acc1 * sc + p * xl1;
            mh = nm;
        }
    }
    float r0, r1;
    if (re > rs) { float inv = 1.f / lh; r0 = acc0 * inv; r1 = acc1 * inv; }
    else { r0 = 0.f; r1 = 0.f; }
    r0 += bias1[f0]; r1 += bias1[f1];
    r0 = (r0 > 0.f) ? r0 : (__expf(r0) - 1.f);
    r1 = (r1 > 0.f) ? r1 : (__expf(r1) - 1.f);
    hpost[v * 128 + f0] = r0;
    hpost[v * 128 + f1] = r1;
}

// ---------------- Layer 2 node transforms: register-tiled LDS GEMM ----------------
// Block = 256 thr (4 waves), 64-node tile. Per-lane 4x4 output tile.
// LDS: hs = h-tile [64][128] XOR-swizzled at float4 granularity (32 KB)
//      ws = one W panel [128][64] natural layout (32 KB)  -> 64 KB total
// k-loop per 4-k step: 4x ds_read_b128 (h, k-quads) + 4x ds_read_b128 (W, f-quads) + 64 FMA.

struct XF2Shared {
    float4 hs[64 * 32];   // slot = node*32 + (kq ^ ((node>>2)&7))
    float4 ws[128 * 16];  // slot = k*16 + fq   (W[k][4fq..4fq+3])
};

__device__ __forceinline__ void xf2_pass(XF2Shared& sm,
                                         const float* __restrict__ W,
                                         const float* __restrict__ b,
                                         float* __restrict__ out,
                                         int v0, int n, int t) {
    __syncthreads();   // h staged / previous pass done reading ws
    {
        const float4* wsrc = (const float4*)W;
#pragma unroll
        for (int i = 0; i < 8; ++i) sm.ws[t + 256 * i] = wsrc[t + 256 * i];
    }
    __syncthreads();

    int lane = t & 63, w = t >> 6;
    int fg = lane & 3, ng = lane >> 2;
    int fq = 4 * w + fg;              // float4 index into the 64-wide output
    int hsw = ng & 7;

    float acc[4][4];
#pragma unroll
    for (int i = 0; i < 4; ++i)
#pragma unroll
        for (int c = 0; c < 4; ++c) acc[i][c] = 0.f;

    for (int kq = 0; kq < 32; ++kq) {
        float4 w0 = sm.ws[(4 * kq + 0) * 16 + fq];
        float4 w1 = sm.ws[(4 * kq + 1) * 16 + fq];
        float4 w2 = sm.ws[(4 * kq + 2) * 16 + fq];
        float4 w3 = sm.ws[(4 * kq + 3) * 16 + fq];
        int ks = kq ^ hsw;
        float4 h0 = sm.hs[(4 * ng + 0) * 32 + ks];
        float4 h1 = sm.hs[(4 * ng + 1) * 32 + ks];
        float4 h2 = sm.hs[(4 * ng + 2) * 32 + ks];
        float4 h3 = sm.hs[(4 * ng + 3) * 32 + ks];
#pragma unroll
        for (int i = 0; i < 4; ++i) {
            float4 h = (i == 0) ? h0 : (i == 1) ? h1 : (i == 2) ? h2 : h3;
            acc[i][0] += h.x * w0.x; acc[i][1] += h.x * w0.y; acc[i][2] += h.x * w0.z; acc[i][3] += h.x * w0.w;
            acc[i][0] += h.y * w1.x; acc[i][1] += h.y * w1.y; acc[i][2] += h.y * w1.z; acc[i][3] += h.y * w1.w;
            acc[i][0] += h.z * w2.x; acc[i][1] += h.z * w2.y; acc[i][2] += h.z * w2.z; acc[i][3] += h.z * w2.w;
            acc[i][0] += h.w * w3.x; acc[i][1] += h.w * w3.y; acc[i][2] += h.w * w3.z; acc[i][3] += h.w * w3.w;
        }
    }

    float4 bf = ((const float4*)b)[fq];
#pragma unroll
    for (int i = 0; i < 4; ++i) {
        int node = v0 + 4 * ng + i;
        if (node < n) {
            float4 r = make_float4(acc[i][0] + bf.x, acc[i][1] + bf.y,
                                   acc[i][2] + bf.z, acc[i][3] + bf.w);
            *(float4*)(out + (size_t)node * 64 + 4 * fq) = r;
        }
    }
}

__global__ __launch_bounds__(256) void k_transform2(
    const float* __restrict__ hpost,
    const float* __restrict__ W_l2, const float* __restrict__ b_l2,
    const float* __restrict__ W_r2, const float* __restrict__ b_r2,
    float* __restrict__ xl2, float* __restrict__ xr2, int n)
{
    __shared__ XF2Shared sm;
    int t = threadIdx.x;
    int v0 = blockIdx.x * 64;
    // stage h tile: thread t -> node = t>>2, sub = t&3; 8 float4 per thread
    {
        int node = t >> 2, sub = t & 3;
        int sw = (node >> 2) & 7;
        bool valid = (v0 + node) < n;
        const float4* src = (const float4*)(hpost + (size_t)(v0 + node) * 128);
#pragma unroll
        for (int i = 0; i < 8; ++i) {
            int kq = sub + 4 * i;
            float4 val = valid ? src[kq] : make_float4(0.f, 0.f, 0.f, 0.f);
            sm.hs[node * 32 + (kq ^ sw)] = val;
        }
    }
    xf2_pass(sm, W_l2, b_l2, xl2, v0, n, t);
    xf2_pass(sm, W_r2, b_r2, xr2, v0, n, t);
}

// ---------------- Layer 2 aggregation: wave per node, lane = feature ----------------

__global__ __launch_bounds__(256) void k_agg2(
    const float* __restrict__ xl2,
    const float* __restrict__ xr2,
    const int* __restrict__ rowp,
    const int* __restrict__ col_src,
    const float2* __restrict__ col_ea,
    const float* __restrict__ W_e2,
    const float* __restrict__ att2,
    const float* __restrict__ bias2,
    float* __restrict__ h2,
    int n)
{
    int wid = (blockIdx.x * blockDim.x + threadIdx.x) >> 6;
    int lane = threadIdx.x & 63;
    if (wid >= n) return;
    int v = wid;
    float We0 = W_e2[lane], We1 = W_e2[64 + lane];
    float a = att2[lane];
    float xr = xr2[v * 64 + lane];
    float mh = -INFINITY, lh = 0.f, acc = 0.f;
    int rs = rowp[v], re = rowp[v + 1];
    for (int cs = rs; cs < re; cs += 64) {
        int cnt = min(64, re - cs);
        int myu = 0; float2 mea = make_float2(0.f, 0.f);
        if (lane < cnt) { myu = col_src[cs + lane]; mea = col_ea[cs + lane]; }
        for (int j = 0; j < cnt; ++j) {
            int u = __shfl(myu, j);
            float ea0 = __shfl(mea.x, j), ea1 = __shfl(mea.y, j);
            float xl = xl2[u * 64 + lane];
            float m = xl + xr + ea0 * We0 + ea1 * We1;
            float ph = fmaxf(m, 0.2f * m) * a;
            ph += __shfl_xor(ph, 1);
            ph += __shfl_xor(ph, 2);
            ph += __shfl_xor(ph, 4);
            ph += __shfl_xor(ph, 8);
            float nm = fmaxf(mh, ph);
            float sc = __expf(mh - nm);
            float p = __expf(ph - nm);
            lh = lh * sc + p;
            acc = acc * sc + p * xl;
            mh = nm;
        }
    }
    float r = (re > rs) ? acc / lh : 0.f;
    h2[v * 64 + lane] = r + bias2[lane];
}

// ---------------- Mean pool over graphs (batch sorted: segmented reduce) ----------------

__global__ __launch_bounds__(256) void k_pool2(const float* __restrict__ h2,
                                               const int* __restrict__ batch,
                                               float* __restrict__ sums, float* __restrict__ cnt,
                                               int n, int chunk) {
    int w = (blockIdx.x * blockDim.x + threadIdx.x) >> 6;
    int lane = threadIdx.x & 63;
    int start = w * chunk;
    if (start >= n) return;
    int end = min(n, start + chunk);
    int g = batch[start];
    float acc = 0.f;
    int c = 0;
    for (int v = start; v < end; ++v) {
        int bg = batch[v];
        if (bg != g) {
            atomicAdd(&sums[g * 64 + lane], acc);
            if (lane == 0) atomicAdd(&cnt[g], (float)c);
            acc = 0.f; c = 0; g = bg;
        }
        acc += h2[(size_t)v * 64 + lane];
        ++c;
    }
    atomicAdd(&sums[g * 64 + lane], acc);
    if (lane == 0) atomicAdd(&cnt[g], (float)c);
}

__global__ void k_final(const float* __restrict__ sums, const float* __restrict__ cnt,
                        float* __restrict__ out, int g) {
    int i = blockIdx.x * blockDim.x + threadIdx.x;
    if (i < g * 64) out[i] = sums[i] / fmaxf(cnt[i >> 6], 1.f);
}

// ---------------- launch ----------------

extern "C" void kernel_launch(void* const* d_in, const int* in_sizes, int n_in,
                              void* d_out, int out_size, void* d_ws, size_t ws_size,
                              hipStream_t stream) {
    const float* x     = (const float*)d_in[0];
    const float* ea    = (const float*)d_in[1];
    const float* W_l1  = (const float*)d_in[2];
    const float* b_l1  = (const float*)d_in[3];
    const float* W_r1  = (const float*)d_in[4];
    const float* b_r1  = (const float*)d_in[5];
    const float* W_e1  = (const float*)d_in[6];
    const float* att1  = (const float*)d_in[7];
    const float* bias1 = (const float*)d_in[8];
    const float* W_l2  = (const float*)d_in[9];
    const float* b_l2  = (const float*)d_in[10];
    const float* W_r2  = (const float*)d_in[11];
    const float* b_r2  = (const float*)d_in[12];
    const float* W_e2  = (const float*)d_in[13];
    const float* att2  = (const float*)d_in[14];
    const float* bias2 = (const float*)d_in[15];
    const int* eidx    = (const int*)d_in[16];
    const int* batch   = (const int*)d_in[17];

    int n = in_sizes[0] / 2;     // 50000
    int e = in_sizes[16] / 2;    // 800000
    int g = out_size / 64;       // 64
    const int* srcI = eidx;
    const int* tgtI = eidx + e;
    int nb = (n + 255) / 256;

    char* w = (char*)d_ws;
    size_t off = 0;
    auto take = [&](size_t bytes) -> char* {
        size_t a = (off + 255) & ~(size_t)255;
        off = a + bytes;
        return w + a;
    };
    float*  hpost   = (float*)take((size_t)n * 128 * 4);
    float*  xl2     = (float*)take((size_t)n * 64 * 4);
    float*  xr2     = (float*)take((size_t)n * 64 * 4);
    float*  h2      = (float*)take((size_t)n * 64 * 4);
    int*    deg     = (int*)take((size_t)n * 4);
    int*    pos     = (int*)take((size_t)n * 4);
    int*    rowp    = (int*)take((size_t)(n + 1) * 4);
    int*    col_src = (int*)take((size_t)e * 4);
    float2* col_ea  = (float2*)take((size_t)e * 8);
    float*  sums    = (float*)take((size_t)g * 64 * 4);
    float*  cnt     = (float*)take((size_t)g * 4);
    int*    bsum    = (int*)take((size_t)nb * 4);
    int*    boff    = (int*)take((size_t)nb * 4);

    hipMemsetAsync(deg, 0, (size_t)n * 4, stream);
    hipMemsetAsync(sums, 0, (size_t)g * 64 * 4, stream);
    hipMemsetAsync(cnt, 0, (size_t)g * 4, stream);

    k_deg<<<(e + 255) / 256, 256, 0, stream>>>(tgtI, deg, e);
    k_scanA<<<nb, 256, 0, stream>>>(deg, rowp, bsum, n);
    k_scanB<<<1, 256, 0, stream>>>(bsum, boff, rowp, nb, n);
    k_scanC<<<nb, 256, 0, stream>>>(rowp, pos, boff, n);
    k_scatter<<<(e + 255) / 256, 256, 0, stream>>>(srcI, tgtI, ea, pos, col_src, col_ea, e);

    int nwaveblocks = (n * 64 + 255) / 256;
    k_agg1<<<nwaveblocks, 256, 0, stream>>>(x, rowp, col_src, col_ea,
                                            W_l1, b_l1, W_r1, b_r1, W_e1, att1, bias1,
                                            hpost, n);
    int ntiles = (n + 63) / 64;
    k_transform2<<<ntiles, 256, 0, stream>>>(hpost, W_l2, b_l2, W_r2, b_r2, xl2, xr2, n);
    k_agg2<<<nwaveblocks, 256, 0, stream>>>(xl2, xr2, rowp, col_src, col_ea,
                                            W_e2, att2, bias2, h2, n);

    int pool_waves = 1024;
    int pool_chunk = (n + pool_waves - 1) / pool_waves;
    k_pool2<<<pool_waves / 4, 256, 0, stream>>>(h2, batch, sums, cnt, n, pool_chunk);
    k_final<<<(g * 64 + 255) / 256, 256, 0, stream>>>(sums, cnt, (float*)d_out, g);
}

// Round 4
// 256.321 us; speedup vs baseline: 3.8687x; 1.2188x over previous
//
#include <hip/hip_runtime.h>
#include <math.h>

// ---------------- CSR build ----------------

__global__ void k_deg(const int* __restrict__ tgt, int* __restrict__ deg, int e) {
    int i = blockIdx.x * blockDim.x + threadIdx.x;
    if (i < e) atomicAdd(&deg[tgt[i]], 1);
}

// parallel scan, stage A: per-block (256-elem tile) exclusive scan via wave shuffles
__global__ __launch_bounds__(256) void k_scanA(const int* __restrict__ deg,
                                               int* __restrict__ excl,
                                               int* __restrict__ bsum, int n) {
    int i = blockIdx.x * 256 + threadIdx.x;
    int lane = threadIdx.x & 63, wv = threadIdx.x >> 6;
    int v = (i < n) ? deg[i] : 0;
    int incl = v;
#pragma unroll
    for (int off = 1; off < 64; off <<= 1) {
        int t = __shfl_up(incl, off);
        if (lane >= off) incl += t;
    }
    __shared__ int ws[4];
    if (lane == 63) ws[wv] = incl;
    __syncthreads();
    int prefix = 0;
    for (int k = 0; k < wv; ++k) prefix += ws[k];
    if (i < n) excl[i] = prefix + incl - v;
    if (threadIdx.x == 255) bsum[blockIdx.x] = prefix + incl;
}

__global__ __launch_bounds__(256) void k_scanB(const int* __restrict__ bsum, int* __restrict__ boff,
                                               int* __restrict__ rowp, int nb, int n) {
    __shared__ int ws[4];
    __shared__ int carry_s;
    int lane = threadIdx.x & 63, wv = threadIdx.x >> 6;
    if (threadIdx.x == 0) carry_s = 0;
    __syncthreads();
    for (int base = 0; base < nb; base += 256) {
        int i = base + threadIdx.x;
        int v = (i < nb) ? bsum[i] : 0;
        int incl = v;
#pragma unroll
        for (int off = 1; off < 64; off <<= 1) {
            int t = __shfl_up(incl, off);
            if (lane >= off) incl += t;
        }
        if (lane == 63) ws[wv] = incl;
        __syncthreads();
        int prefix = carry_s;
        for (int k = 0; k < wv; ++k) prefix += ws[k];
        if (i < nb) boff[i] = prefix + incl - v;
        __syncthreads();
        if (threadIdx.x == 255) carry_s = prefix + incl;
        __syncthreads();
    }
    if (threadIdx.x == 0) rowp[n] = carry_s;
}

__global__ void k_scanC(int* __restrict__ rowp, int* __restrict__ pos,
                        const int* __restrict__ boff, int n) {
    int i = blockIdx.x * 256 + threadIdx.x;
    if (i < n) {
        int r = rowp[i] + boff[blockIdx.x];
        rowp[i] = r;
        pos[i] = r;
    }
}

// scatter: edge record = {x[src].x, x[src].y, ea0, ea1}; col_src kept separately for layer 2
__global__ void k_scatter(const int* __restrict__ src, const int* __restrict__ tgt,
                          const float* __restrict__ ea, const float2* __restrict__ x2,
                          int* __restrict__ pos,
                          int* __restrict__ col_src, float4* __restrict__ col_rec, int e) {
    int i = blockIdx.x * blockDim.x + threadIdx.x;
    if (i < e) {
        int t = tgt[i];
        int s = src[i];
        float2 xv = x2[s];
        float2 ev = ((const float2*)ea)[i];
        int slot = atomicAdd(&pos[t], 1);
        col_src[slot] = s;
        col_rec[slot] = make_float4(xv.x, xv.y, ev.x, ev.y);
    }
}

// ---------------- Layer 1: fused transform + 4-edge-batched online softmax ----------------
// wave per node; lane l owns features 2l,2l+1; head = l>>2 (reduce over 4-lane groups).
// All edge inputs come from one uniform s_load_dwordx4 per edge (no gathers, no bcast shfl).

__global__ __launch_bounds__(256) void k_agg1(
    const float* __restrict__ x,
    const int* __restrict__ rowp,
    const float4* __restrict__ col_rec,
    const float* __restrict__ W_l1, const float* __restrict__ b_l1,
    const float* __restrict__ W_r1, const float* __restrict__ b_r1,
    const float* __restrict__ W_e1,
    const float* __restrict__ att1,
    const float* __restrict__ bias1,
    float* __restrict__ hpost,
    int n)
{
    int wid = (blockIdx.x * blockDim.x + threadIdx.x) >> 6;
    if (wid >= n) return;
    int v = __builtin_amdgcn_readfirstlane(wid);
    int lane = threadIdx.x & 63;
    int f0 = 2 * lane, f1 = 2 * lane + 1;

    float Wl00 = W_l1[f0], Wl10 = W_l1[128 + f0], bl0 = b_l1[f0];
    float Wl01 = W_l1[f1], Wl11 = W_l1[128 + f1], bl1 = b_l1[f1];
    float We00 = W_e1[f0], We10 = W_e1[128 + f0];
    float We01 = W_e1[f1], We11 = W_e1[128 + f1];
    float a0 = att1[f0], a1 = att1[f1];

    float xv0 = x[2 * v], xv1 = x[2 * v + 1];
    float xrA = xv0 * W_r1[f0] + xv1 * W_r1[128 + f0] + b_r1[f0];
    float xrB = xv0 * W_r1[f1] + xv1 * W_r1[128 + f1] + b_r1[f1];

    float mh = -INFINITY, lh = 0.f;
    float acc0 = 0.f, acc1 = 0.f;
    int rs = rowp[v], re = rowp[v + 1];

    for (int cs = rs; cs < re; cs += 4) {
        int j1 = min(cs + 1, re - 1), j2 = min(cs + 2, re - 1), j3 = min(cs + 3, re - 1);
        float4 r0 = col_rec[cs];
        float4 r1 = col_rec[j1];
        float4 r2 = col_rec[j2];
        float4 r3 = col_rec[j3];

        float xlA0, xlA1, xlA2, xlA3, xlB0, xlB1, xlB2, xlB3;
        float ph0, ph1, ph2, ph3;
#define EDGE1(K, R, VALID)                                                   \
        {                                                                    \
            float xa = fmaf(R.x, Wl00, fmaf(R.y, Wl10, bl0));                \
            float xb = fmaf(R.x, Wl01, fmaf(R.y, Wl11, bl1));                \
            xlA##K = xa; xlB##K = xb;                                        \
            float m0 = xa + xrA + R.z * We00 + R.w * We10;                   \
            float m1 = xb + xrB + R.z * We01 + R.w * We11;                   \
            float p = fmaxf(m0, 0.2f * m0) * a0 + fmaxf(m1, 0.2f * m1) * a1; \
            ph##K = (VALID) ? p : -INFINITY;                                 \
        }
        EDGE1(0, r0, true)
        EDGE1(1, r1, cs + 1 < re)
        EDGE1(2, r2, cs + 2 < re)
        EDGE1(3, r3, cs + 3 < re)
#undef EDGE1

        // butterfly-transpose reduce over the 4-lane head group: lane ends with e[lane&3]
        bool b0 = lane & 1, b1 = lane & 2;
        float s01 = (b0 ? ph1 : ph0) + __shfl_xor(b0 ? ph0 : ph1, 1);
        float s23 = (b0 ? ph3 : ph2) + __shfl_xor(b0 ? ph2 : ph3, 1);
        float s   = (b1 ? s23 : s01) + __shfl_xor(b1 ? s01 : s23, 2);

        float mx = fmaxf(s, __shfl_xor(s, 1));
        mx = fmaxf(mx, __shfl_xor(mx, 2));
        float nm = fmaxf(mh, mx);
        float pl = __expf(s - nm);          // lane holds p[lane&3]
        int base = lane & 60;
        float p0 = __shfl(pl, base + 0);
        float p1 = __shfl(pl, base + 1);
        float p2 = __shfl(pl, base + 2);
        float p3 = __shfl(pl, base + 3);
        float sc = __expf(mh - nm);
        lh = lh * sc + ((p0 + p1) + (p2 + p3));
        acc0 = acc0 * sc + p0 * xlA0 + p1 * xlA1 + p2 * xlA2 + p3 * xlA3;
        acc1 = acc1 * sc + p0 * xlB0 + p1 * xlB1 + p2 * xlB2 + p3 * xlB3;
        mh = nm;
    }

    float r0o, r1o;
    if (re > rs) { float inv = 1.f / lh; r0o = acc0 * inv; r1o = acc1 * inv; }
    else { r0o = 0.f; r1o = 0.f; }
    r0o += bias1[f0]; r1o += bias1[f1];
    r0o = (r0o > 0.f) ? r0o : (__expf(r0o) - 1.f);
    r1o = (r1o > 0.f) ? r1o : (__expf(r1o) - 1.f);
    *(float2*)(hpost + (size_t)v * 128 + f0) = make_float2(r0o, r1o);
}

// ---------------- Layer 2 node transforms: register-tiled LDS GEMM ----------------

struct XF2Shared {
    float4 hs[64 * 32];   // slot = node*32 + (kq ^ ((node>>2)&7))
    float4 ws[128 * 16];  // slot = k*16 + fq
};

__device__ __forceinline__ void xf2_pass(XF2Shared& sm,
                                         const float* __restrict__ W,
                                         const float* __restrict__ b,
                                         float* __restrict__ out,
                                         int v0, int n, int t) {
    __syncthreads();
    {
        const float4* wsrc = (const float4*)W;
#pragma unroll
        for (int i = 0; i < 8; ++i) sm.ws[t + 256 * i] = wsrc[t + 256 * i];
    }
    __syncthreads();

    int lane = t & 63, w = t >> 6;
    int fg = lane & 3, ng = lane >> 2;
    int fq = 4 * w + fg;
    int hsw = ng & 7;

    float acc[4][4];
#pragma unroll
    for (int i = 0; i < 4; ++i)
#pragma unroll
        for (int c = 0; c < 4; ++c) acc[i][c] = 0.f;

    for (int kq = 0; kq < 32; ++kq) {
        float4 w0 = sm.ws[(4 * kq + 0) * 16 + fq];
        float4 w1 = sm.ws[(4 * kq + 1) * 16 + fq];
        float4 w2 = sm.ws[(4 * kq + 2) * 16 + fq];
        float4 w3 = sm.ws[(4 * kq + 3) * 16 + fq];
        int ks = kq ^ hsw;
        float4 h0 = sm.hs[(4 * ng + 0) * 32 + ks];
        float4 h1 = sm.hs[(4 * ng + 1) * 32 + ks];
        float4 h2 = sm.hs[(4 * ng + 2) * 32 + ks];
        float4 h3 = sm.hs[(4 * ng + 3) * 32 + ks];
#pragma unroll
        for (int i = 0; i < 4; ++i) {
            float4 h = (i == 0) ? h0 : (i == 1) ? h1 : (i == 2) ? h2 : h3;
            acc[i][0] += h.x * w0.x; acc[i][1] += h.x * w0.y; acc[i][2] += h.x * w0.z; acc[i][3] += h.x * w0.w;
            acc[i][0] += h.y * w1.x; acc[i][1] += h.y * w1.y; acc[i][2] += h.y * w1.z; acc[i][3] += h.y * w1.w;
            acc[i][0] += h.z * w2.x; acc[i][1] += h.z * w2.y; acc[i][2] += h.z * w2.z; acc[i][3] += h.z * w2.w;
            acc[i][0] += h.w * w3.x; acc[i][1] += h.w * w3.y; acc[i][2] += h.w * w3.z; acc[i][3] += h.w * w3.w;
        }
    }

    float4 bf = ((const float4*)b)[fq];
#pragma unroll
    for (int i = 0; i < 4; ++i) {
        int node = v0 + 4 * ng + i;
        if (node < n) {
            float4 r = make_float4(acc[i][0] + bf.x, acc[i][1] + bf.y,
                                   acc[i][2] + bf.z, acc[i][3] + bf.w);
            *(float4*)(out + (size_t)node * 64 + 4 * fq) = r;
        }
    }
}

__global__ __launch_bounds__(256) void k_transform2(
    const float* __restrict__ hpost,
    const float* __restrict__ W_l2, const float* __restrict__ b_l2,
    const float* __restrict__ W_r2, const float* __restrict__ b_r2,
    float* __restrict__ xl2, float* __restrict__ xr2, int n)
{
    __shared__ XF2Shared sm;
    int t = threadIdx.x;
    int v0 = blockIdx.x * 64;
    {
        int node = t >> 2, sub = t & 3;
        int sw = (node >> 2) & 7;
        bool valid = (v0 + node) < n;
        const float4* src = (const float4*)(hpost + (size_t)(v0 + node) * 128);
#pragma unroll
        for (int i = 0; i < 8; ++i) {
            int kq = sub + 4 * i;
            float4 val = valid ? src[kq] : make_float4(0.f, 0.f, 0.f, 0.f);
            sm.hs[node * 32 + (kq ^ sw)] = val;
        }
    }
    xf2_pass(sm, W_l2, b_l2, xl2, v0, n, t);
    xf2_pass(sm, W_r2, b_r2, xr2, v0, n, t);
}

// ---------------- Layer 2 aggregation: 4-edge-batched online softmax ----------------
// wave per node, lane = feature; head = lane>>4 (reduce over 16-lane groups)

__global__ __launch_bounds__(256) void k_agg2(
    const float* __restrict__ xl2,
    const float* __restrict__ xr2,
    const int* __restrict__ rowp,
    const int* __restrict__ col_src,
    const float4* __restrict__ col_rec,
    const float* __restrict__ W_e2,
    const float* __restrict__ att2,
    const float* __restrict__ bias2,
    float* __restrict__ h2,
    int n)
{
    int wid = (blockIdx.x * blockDim.x + threadIdx.x) >> 6;
    if (wid >= n) return;
    int v = __builtin_amdgcn_readfirstlane(wid);
    int lane = threadIdx.x & 63;
    float We0 = W_e2[lane], We1 = W_e2[64 + lane];
    float a = att2[lane];
    float xr = xr2[(size_t)v * 64 + lane];
    float mh = -INFINITY, lh = 0.f, acc = 0.f;
    int rs = rowp[v], re = rowp[v + 1];
    const float2* eap = (const float2*)col_rec;   // ea at odd float2 slots

    for (int cs = rs; cs < re; cs += 4) {
        int j1 = min(cs + 1, re - 1), j2 = min(cs + 2, re - 1), j3 = min(cs + 3, re - 1);
        int u0 = col_src[cs], u1 = col_src[j1], u2 = col_src[j2], u3 = col_src[j3];
        float2 e0 = eap[2 * cs + 1], e1 = eap[2 * j1 + 1];
        float2 e2 = eap[2 * j2 + 1], e3 = eap[2 * j3 + 1];
        float xl_0 = xl2[(size_t)u0 * 64 + lane];
        float xl_1 = xl2[(size_t)u1 * 64 + lane];
        float xl_2 = xl2[(size_t)u2 * 64 + lane];
        float xl_3 = xl2[(size_t)u3 * 64 + lane];

        float ph0, ph1, ph2, ph3;
#define EDGE2(K, EV, XL, VALID)                          \
        {                                                \
            float m = XL + xr + EV.x * We0 + EV.y * We1; \
            float p = fmaxf(m, 0.2f * m) * a;            \
            ph##K = (VALID) ? p : -INFINITY;             \
        }
        EDGE2(0, e0, xl_0, true)
        EDGE2(1, e1, xl_1, cs + 1 < re)
        EDGE2(2, e2, xl_2, cs + 2 < re)
        EDGE2(3, e3, xl_3, cs + 3 < re)
#undef EDGE2

        // butterfly-transpose reduce over the 16-lane head group
        bool b0 = lane & 1, b1 = lane & 2;
        float s01 = (b0 ? ph1 : ph0) + __shfl_xor(b0 ? ph0 : ph1, 1);
        float s23 = (b0 ? ph3 : ph2) + __shfl_xor(b0 ? ph2 : ph3, 1);
        float s   = (b1 ? s23 : s01) + __shfl_xor(b1 ? s01 : s23, 2);
        s += __shfl_xor(s, 4);
        s += __shfl_xor(s, 8);                    // lane holds e[lane&3] for its head

        float mx = fmaxf(s, __shfl_xor(s, 1));
        mx = fmaxf(mx, __shfl_xor(mx, 2));
        float nm = fmaxf(mh, mx);
        float pl = __expf(s - nm);
        int base = lane & 48;
        float p0 = __shfl(pl, base + 0);
        float p1 = __shfl(pl, base + 1);
        float p2 = __shfl(pl, base + 2);
        float p3 = __shfl(pl, base + 3);
        float sc = __expf(mh - nm);
        lh = lh * sc + ((p0 + p1) + (p2 + p3));
        acc = acc * sc + p0 * xl_0 + p1 * xl_1 + p2 * xl_2 + p3 * xl_3;
        mh = nm;
    }
    float r = (re > rs) ? acc / lh : 0.f;
    h2[(size_t)v * 64 + lane] = r + bias2[lane];
}

// ---------------- Mean pool over graphs (batch sorted: segmented reduce) ----------------

__global__ __launch_bounds__(256) void k_pool2(const float* __restrict__ h2,
                                               const int* __restrict__ batch,
                                               float* __restrict__ sums, float* __restrict__ cnt,
                                               int n, int chunk) {
    int w = (blockIdx.x * blockDim.x + threadIdx.x) >> 6;
    int lane = threadIdx.x & 63;
    int start = w * chunk;
    if (start >= n) return;
    int end = min(n, start + chunk);
    int g = batch[start];
    float acc = 0.f;
    int c = 0;
    for (int v = start; v < end; ++v) {
        int bg = batch[v];
        if (bg != g) {
            atomicAdd(&sums[g * 64 + lane], acc);
            if (lane == 0) atomicAdd(&cnt[g], (float)c);
            acc = 0.f; c = 0; g = bg;
        }
        acc += h2[(size_t)v * 64 + lane];
        ++c;
    }
    atomicAdd(&sums[g * 64 + lane], acc);
    if (lane == 0) atomicAdd(&cnt[g], (float)c);
}

__global__ void k_final(const float* __restrict__ sums, const float* __restrict__ cnt,
                        float* __restrict__ out, int g) {
    int i = blockIdx.x * blockDim.x + threadIdx.x;
    if (i < g * 64) out[i] = sums[i] / fmaxf(cnt[i >> 6], 1.f);
}

// ---------------- launch ----------------

extern "C" void kernel_launch(void* const* d_in, const int* in_sizes, int n_in,
                              void* d_out, int out_size, void* d_ws, size_t ws_size,
                              hipStream_t stream) {
    const float* x     = (const float*)d_in[0];
    const float* ea    = (const float*)d_in[1];
    const float* W_l1  = (const float*)d_in[2];
    const float* b_l1  = (const float*)d_in[3];
    const float* W_r1  = (const float*)d_in[4];
    const float* b_r1  = (const float*)d_in[5];
    const float* W_e1  = (const float*)d_in[6];
    const float* att1  = (const float*)d_in[7];
    const float* bias1 = (const float*)d_in[8];
    const float* W_l2  = (const float*)d_in[9];
    const float* b_l2  = (const float*)d_in[10];
    const float* W_r2  = (const float*)d_in[11];
    const float* b_r2  = (const float*)d_in[12];
    const float* W_e2  = (const float*)d_in[13];
    const float* att2  = (const float*)d_in[14];
    const float* bias2 = (const float*)d_in[15];
    const int* eidx    = (const int*)d_in[16];
    const int* batch   = (const int*)d_in[17];

    int n = in_sizes[0] / 2;     // 50000
    int e = in_sizes[16] / 2;    // 800000
    int g = out_size / 64;       // 64
    const int* srcI = eidx;
    const int* tgtI = eidx + e;
    int nb = (n + 255) / 256;

    char* w = (char*)d_ws;
    size_t off = 0;
    auto take = [&](size_t bytes) -> char* {
        size_t a = (off + 255) & ~(size_t)255;
        off = a + bytes;
        return w + a;
    };
    float*  hpost   = (float*)take((size_t)n * 128 * 4);
    float*  h2      = hpost;     // alias: hpost dead after k_transform2
    float*  xl2     = (float*)take((size_t)n * 64 * 4);
    float*  xr2     = (float*)take((size_t)n * 64 * 4);
    int*    deg     = (int*)take((size_t)n * 4);
    int*    pos     = (int*)take((size_t)n * 4);
    int*    rowp    = (int*)take((size_t)(n + 1) * 4);
    int*    col_src = (int*)take((size_t)e * 4);
    float4* col_rec = (float4*)take((size_t)e * 16);
    float*  sums    = (float*)take((size_t)g * 64 * 4);
    float*  cnt     = (float*)take((size_t)g * 4);
    int*    bsum    = (int*)take((size_t)nb * 4);
    int*    boff    = (int*)take((size_t)nb * 4);

    hipMemsetAsync(deg, 0, (size_t)n * 4, stream);
    hipMemsetAsync(sums, 0, (size_t)g * 64 * 4, stream);
    hipMemsetAsync(cnt, 0, (size_t)g * 4, stream);

    k_deg<<<(e + 255) / 256, 256, 0, stream>>>(tgtI, deg, e);
    k_scanA<<<nb, 256, 0, stream>>>(deg, rowp, bsum, n);
    k_scanB<<<1, 256, 0, stream>>>(bsum, boff, rowp, nb, n);
    k_scanC<<<nb, 256, 0, stream>>>(rowp, pos, boff, n);
    k_scatter<<<(e + 255) / 256, 256, 0, stream>>>(srcI, tgtI, ea, (const float2*)x,
                                                   pos, col_src, col_rec, e);

    int nwaveblocks = (n * 64 + 255) / 256;
    k_agg1<<<nwaveblocks, 256, 0, stream>>>(x, rowp, col_rec,
                                            W_l1, b_l1, W_r1, b_r1, W_e1, att1, bias1,
                                            hpost, n);
    int ntiles = (n + 63) / 64;
    k_transform2<<<ntiles, 256, 0, stream>>>(hpost, W_l2, b_l2, W_r2, b_r2, xl2, xr2, n);
    k_agg2<<<nwaveblocks, 256, 0, stream>>>(xl2, xr2, rowp, col_src, col_rec,
                                            W_e2, att2, bias2, h2, n);

    int pool_waves = 1024;
    int pool_chunk = (n + pool_waves - 1) / pool_waves;
    k_pool2<<<pool_waves / 4, 256, 0, stream>>>(h2, batch, sums, cnt, n, pool_chunk);
    k_final<<<(g * 64 + 255) / 256, 256, 0, stream>>>(sums, cnt, (float*)d_out, g);
}